// Round 4
// baseline (315.051 us; speedup 1.0000x reference)
//
#include <hip/hip_runtime.h>
#include <stdint.h>

constexpr int NN = 20000;
constexpr int FF = 256;
constexpr int NODES_PER_BLOCK = 4;   // 256 threads, 64 threads (1 wave) per node

typedef float v4f __attribute__((ext_vector_type(4)));

// CG coefficients: addrspace(4) + wave-uniform address -> s_load -> SGPR.
typedef const __attribute__((address_space(4))) float* cgp;
#define CGP(p) ((cgp)(uintptr_t)(p))

__device__ __forceinline__ v4f ld4(const float* p) { return *(const v4f*)p; }
__device__ __forceinline__ void st4(float* p, v4f v) { *(v4f*)p = v; }

// Force the coefficient into an SGPR operand of a scalar VALU op.
__device__ __forceinline__ float sfma(float c, float p, float acc) {
    float d;
    asm("v_fma_f32 %0, %1, %2, %3" : "=v"(d) : "s"(c), "v"(p), "v"(acc));
    return d;
}
__device__ __forceinline__ float smul(float c, float p) {
    float d;
    asm("v_mul_f32 %0, %1, %2" : "=v"(d) : "s"(c), "v"(p));
    return d;
}

// t[k] (+)= cg[ijDO + k] * p   across 4 feature components; FIRST folds init.
template<int DO>
__device__ __forceinline__ void addk(cgp cg, int ijDO, v4f p, v4f* t, bool first) {
#pragma unroll
    for (int k = 0; k < DO; ++k) {
        const float c = cg[ijDO + k];
        if (first) {
            t[k].x = smul(c, p.x); t[k].y = smul(c, p.y);
            t[k].z = smul(c, p.z); t[k].w = smul(c, p.w);
        } else {
            t[k].x = sfma(c, p.x, t[k].x); t[k].y = sfma(c, p.y, t[k].y);
            t[k].z = sfma(c, p.z, t[k].z); t[k].w = sfma(c, p.w, t[k].w);
        }
    }
}

__device__ __forceinline__ v4f vfma(v4f a, v4f b, v4f c) {
    return __builtin_elementwise_fma(a, b, c);
}

__global__ void __launch_bounds__(256)
__attribute__((amdgpu_waves_per_eu(2, 2)))
selfmix_kernel(
    const float* __restrict__ x0, const float* __restrict__ x1,
    const float* __restrict__ x2, const float* __restrict__ x3,
    const float* __restrict__ keep0, const float* __restrict__ keep1,
    const float* __restrict__ keep2, const float* __restrict__ keep3,
    const float* __restrict__ mix011, const float* __restrict__ cg011,
    const float* __restrict__ mix022, const float* __restrict__ cg022,
    const float* __restrict__ mix033, const float* __restrict__ cg033,
    const float* __restrict__ mix121, const float* __restrict__ cg121,
    const float* __restrict__ mix122, const float* __restrict__ cg122,
    const float* __restrict__ mix123, const float* __restrict__ cg123,
    const float* __restrict__ mix132, const float* __restrict__ cg132,
    const float* __restrict__ mix133, const float* __restrict__ cg133,
    const float* __restrict__ mix231, const float* __restrict__ cg231,
    const float* __restrict__ mix232, const float* __restrict__ cg232,
    const float* __restrict__ mix233, const float* __restrict__ cg233,
    float* __restrict__ out)
{
    const int wid  = threadIdx.x >> 6;          // wave id in block = node sub-index
    const int lane = threadIdx.x & 63;
    const int n    = blockIdx.x * NODES_PER_BLOCK + wid;
    const int f0   = lane * 4;                   // 4 consecutive features

    // ---- load x fragments (16 B/lane, wave covers the full 256-f row) ----
    v4f a0 = ld4(x0 + n * FF + f0);
    v4f a1[3], a2[5], a3[7];
#pragma unroll
    for (int i = 0; i < 3; ++i) a1[i] = ld4(x1 + (n * 3 + i) * FF + f0);
#pragma unroll
    for (int i = 0; i < 5; ++i) a2[i] = ld4(x2 + (n * 5 + i) * FF + f0);
#pragma unroll
    for (int i = 0; i < 7; ++i) a3[i] = ld4(x3 + (n * 7 + i) * FF + f0);

    // ---- keep path ----
    v4f y0 = ld4(keep0 + f0) * a0;
    v4f y1[3], y2[5], y3[7];
    {
        const v4f k1 = ld4(keep1 + f0);
#pragma unroll
        for (int i = 0; i < 3; ++i) y1[i] = k1 * a1[i];
        const v4f k2 = ld4(keep2 + f0);
#pragma unroll
        for (int i = 0; i < 5; ++i) y2[i] = k2 * a2[i];
        const v4f k3 = ld4(keep3 + f0);
#pragma unroll
        for (int i = 0; i < 7; ++i) y3[i] = k3 * a3[i];
    }

    // ---- group (0,1) -> L=1 ----
    {
        const v4f m = ld4(mix011 + f0);
        cgp cg = CGP(cg011);
        v4f t[3];
#pragma unroll
        for (int j = 0; j < 3; ++j)
            addk<3>(cg, j * 3, a0 * a1[j], t, j == 0);
#pragma unroll
        for (int k = 0; k < 3; ++k) y1[k] = vfma(m, t[k], y1[k]);
    }

    // ---- group (0,2) -> L=2 ----
    {
        const v4f m = ld4(mix022 + f0);
        cgp cg = CGP(cg022);
        v4f t[5];
#pragma unroll
        for (int j = 0; j < 5; ++j)
            addk<5>(cg, j * 5, a0 * a2[j], t, j == 0);
#pragma unroll
        for (int k = 0; k < 5; ++k) y2[k] = vfma(m, t[k], y2[k]);
    }

    // ---- group (0,3) -> L=3 ----
    {
        const v4f m = ld4(mix033 + f0);
        cgp cg = CGP(cg033);
        v4f t[7];
#pragma unroll
        for (int j = 0; j < 7; ++j)
            addk<7>(cg, j * 7, a0 * a3[j], t, j == 0);
#pragma unroll
        for (int k = 0; k < 7; ++k) y3[k] = vfma(m, t[k], y3[k]);
    }
    // a0 dead from here.

    // ---- group (1,2) -> L=1,2,3 (shared products) ----
    {
        const v4f mA = ld4(mix121 + f0), mB = ld4(mix122 + f0), mC = ld4(mix123 + f0);
        cgp c1 = CGP(cg121);
        cgp c2 = CGP(cg122);
        cgp c3 = CGP(cg123);
        v4f t1[3], t2[5], t3[7];
#pragma unroll
        for (int i = 0; i < 3; ++i) {
#pragma unroll
            for (int j = 0; j < 5; ++j) {
                const int ij = i * 5 + j;
                const v4f p = a1[i] * a2[j];
                addk<3>(c1, ij * 3, p, t1, ij == 0);
                addk<5>(c2, ij * 5, p, t2, ij == 0);
                addk<7>(c3, ij * 7, p, t3, ij == 0);
            }
        }
#pragma unroll
        for (int k = 0; k < 3; ++k) y1[k] = vfma(mA, t1[k], y1[k]);
#pragma unroll
        for (int k = 0; k < 5; ++k) y2[k] = vfma(mB, t2[k], y2[k]);
#pragma unroll
        for (int k = 0; k < 7; ++k) y3[k] = vfma(mC, t3[k], y3[k]);
    }

    // ---- group (1,3) -> L=2,3 (shared products) ----
    {
        const v4f mB = ld4(mix132 + f0), mC = ld4(mix133 + f0);
        cgp c2 = CGP(cg132);
        cgp c3 = CGP(cg133);
        v4f t2[5], t3[7];
#pragma unroll
        for (int i = 0; i < 3; ++i) {
#pragma unroll
            for (int j = 0; j < 7; ++j) {
                const int ij = i * 7 + j;
                const v4f p = a1[i] * a3[j];
                addk<5>(c2, ij * 5, p, t2, ij == 0);
                addk<7>(c3, ij * 7, p, t3, ij == 0);
            }
        }
#pragma unroll
        for (int k = 0; k < 5; ++k) y2[k] = vfma(mB, t2[k], y2[k]);
#pragma unroll
        for (int k = 0; k < 7; ++k) y3[k] = vfma(mC, t3[k], y3[k]);
    }
    // a1 dead from here.

    // ---- group (2,3) -> L=1,2,3 (shared products) ----
    {
        const v4f mA = ld4(mix231 + f0), mB = ld4(mix232 + f0), mC = ld4(mix233 + f0);
        cgp c1 = CGP(cg231);
        cgp c2 = CGP(cg232);
        cgp c3 = CGP(cg233);
        v4f t1[3], t2[5], t3[7];
#pragma unroll
        for (int i = 0; i < 5; ++i) {
#pragma unroll
            for (int j = 0; j < 7; ++j) {
                const int ij = i * 7 + j;
                const v4f p = a2[i] * a3[j];
                addk<3>(c1, ij * 3, p, t1, ij == 0);
                addk<5>(c2, ij * 5, p, t2, ij == 0);
                addk<7>(c3, ij * 7, p, t3, ij == 0);
            }
        }
#pragma unroll
        for (int k = 0; k < 3; ++k) y1[k] = vfma(mA, t1[k], y1[k]);
#pragma unroll
        for (int k = 0; k < 5; ++k) y2[k] = vfma(mB, t2[k], y2[k]);
#pragma unroll
        for (int k = 0; k < 7; ++k) y3[k] = vfma(mC, t3[k], y3[k]);
    }

    // ---- store (concatenated outputs: y0 | y1 | y2 | y3) ----
    float* o0 = out;                          // N*1*F
    float* o1 = out + (size_t)NN * FF;        // N*3*F
    float* o2 = out + (size_t)NN * 4 * FF;    // N*5*F
    float* o3 = out + (size_t)NN * 9 * FF;    // N*7*F

    st4(o0 + n * FF + f0, y0);
#pragma unroll
    for (int k = 0; k < 3; ++k) st4(o1 + (n * 3 + k) * FF + f0, y1[k]);
#pragma unroll
    for (int k = 0; k < 5; ++k) st4(o2 + (n * 5 + k) * FF + f0, y2[k]);
#pragma unroll
    for (int k = 0; k < 7; ++k) st4(o3 + (n * 7 + k) * FF + f0, y3[k]);
}

extern "C" void kernel_launch(void* const* d_in, const int* in_sizes, int n_in,
                              void* d_out, int out_size, void* d_ws, size_t ws_size,
                              hipStream_t stream) {
    const float* x0 = (const float*)d_in[0];
    const float* x1 = (const float*)d_in[1];
    const float* x2 = (const float*)d_in[2];
    const float* x3 = (const float*)d_in[3];
    const float* keep0 = (const float*)d_in[4];
    const float* keep1 = (const float*)d_in[5];
    const float* keep2 = (const float*)d_in[6];
    const float* keep3 = (const float*)d_in[7];
    const float* mix011 = (const float*)d_in[8];
    const float* cg011  = (const float*)d_in[9];
    const float* mix022 = (const float*)d_in[10];
    const float* cg022  = (const float*)d_in[11];
    const float* mix033 = (const float*)d_in[12];
    const float* cg033  = (const float*)d_in[13];
    const float* mix121 = (const float*)d_in[14];
    const float* cg121  = (const float*)d_in[15];
    const float* mix122 = (const float*)d_in[16];
    const float* cg122  = (const float*)d_in[17];
    const float* mix123 = (const float*)d_in[18];
    const float* cg123  = (const float*)d_in[19];
    const float* mix132 = (const float*)d_in[20];
    const float* cg132  = (const float*)d_in[21];
    const float* mix133 = (const float*)d_in[22];
    const float* cg133  = (const float*)d_in[23];
    const float* mix231 = (const float*)d_in[24];
    const float* cg231  = (const float*)d_in[25];
    const float* mix232 = (const float*)d_in[26];
    const float* cg232  = (const float*)d_in[27];
    const float* mix233 = (const float*)d_in[28];
    const float* cg233  = (const float*)d_in[29];

    dim3 grid(NN / NODES_PER_BLOCK);  // 5000
    dim3 block(256);                  // 4 waves = 4 nodes
    hipLaunchKernelGGL(selfmix_kernel, grid, block, 0, stream,
                       x0, x1, x2, x3,
                       keep0, keep1, keep2, keep3,
                       mix011, cg011, mix022, cg022, mix033, cg033,
                       mix121, cg121, mix122, cg122, mix123, cg123,
                       mix132, cg132, mix133, cg133,
                       mix231, cg231, mix232, cg232, mix233, cg233,
                       (float*)d_out);
}